// Round 5
// baseline (1474.787 us; speedup 1.0000x reference)
//
#include <hip/hip_runtime.h>
#include <hip/hip_bf16.h>
#include <math.h>

#define D 2048
#define H 256
#define E 16
#define TMB 32                    // tokens per block
#define BK 32                     // k-chunk; kz quarter = 8
#define LDW 36                    // staging row stride (floats)
#define THREADS 512
#define NCH (D / BK)              // 64
#define XS_OFF 0
#define WS_OFF (TMB * LDW)        // 1152
#define SB_OFF 0                  // sum buffer [32][260] (aliases staging)
#define SB_LDW 260
#define WG_OFF (TMB * SB_LDW)     // 8320
#define LB_OFF (WG_OFF + E * H)   // 12416
#define Z_OFF  (LB_OFF + 16)      // 12432
#define SMEM_FLOATS 12448         // 49.8 KB -> 2 blocks/CU
#define WS_STRIDE 20

__global__ __launch_bounds__(THREADS, 4)
void router_main(const float* __restrict__ x, const float* __restrict__ Wp,
                 const float* __restrict__ Wg, const float* __restrict__ lnw_g,
                 const float* __restrict__ lnb_g, const float* __restrict__ temp_g,
                 float* __restrict__ out_rw, float* __restrict__ out_disp,
                 float* __restrict__ ws_part)
{
    __shared__ __align__(16) float smem[SMEM_FLOATS];
    const int t    = threadIdx.x;
    const int hg   = t & 31;          // h-group: h = hg + 32j   (lane bits 0-4)
    const int kzL  = (t >> 5) & 1;    // k-split low (lane bit 5)
    const int tg   = (t >> 6) & 3;    // token group (wave bits): tok = tg*8+i
    const int kzH  = t >> 8;          // k-split high (wave bit)
    const int kz   = kzH * 2 + kzL;   // k-quarter 0..3
    const int r8   = t >> 3;          // staging row 0..63
    const int c8   = (t & 7) << 2;    // staging col
    const int tok0 = blockIdx.x * TMB;

    float acc[8][8];
    #pragma unroll
    for (int i = 0; i < 8; ++i)
        #pragma unroll
        for (int j = 0; j < 8; ++j) acc[i][j] = 0.f;

    const float* xsp = &smem[XS_OFF + (tg * 8) * LDW + kz * 8];
    const float* wsp = &smem[WS_OFF + hg * LDW + kz * 8];

    for (int c = 0; c < NCH; ++c) {
        const int k0 = c * BK;
        __syncthreads();                       // prior chunk's LDS reads done
        #pragma unroll
        for (int p = 0; p < 4; ++p) {
            const float4 v = *(const float4*)&Wp[(size_t)(p * 64 + r8) * D + k0 + c8];
            *(float4*)&smem[WS_OFF + (p * 64 + r8) * LDW + c8] = v;
        }
        if (t < 256) {                         // waves 0-3: x tile 32x32
            const float4 v = *(const float4*)&x[(size_t)(tok0 + (t >> 3)) * D + k0 + c8];
            *(float4*)&smem[XS_OFF + (t >> 3) * LDW + c8] = v;
        }
        __syncthreads();

        #pragma unroll
        for (int kk = 0; kk < 8; kk += 4) {    // this kz-quarter's 8 k
            float4 wv[8];
            #pragma unroll
            for (int j = 0; j < 8; ++j)
                wv[j] = *(const float4*)&wsp[j * 32 * LDW + kk];
            #pragma unroll
            for (int i = 0; i < 8; ++i) {
                const float4 xa = *(const float4*)&xsp[i * LDW + kk];
                #pragma unroll
                for (int j = 0; j < 8; ++j) {
                    acc[i][j] = fmaf(xa.x, wv[j].x, acc[i][j]);
                    acc[i][j] = fmaf(xa.y, wv[j].y, acc[i][j]);
                    acc[i][j] = fmaf(xa.z, wv[j].z, acc[i][j]);
                    acc[i][j] = fmaf(xa.w, wv[j].w, acc[i][j]);
                }
            }
        }
    }

    // ---- kzL reduction: in-wave butterfly (lane bit 5) ----
    #pragma unroll
    for (int i = 0; i < 8; ++i)
        #pragma unroll
        for (int j = 0; j < 8; ++j)
            acc[i][j] += __shfl_xor(acc[i][j], 32);

    __syncthreads();                            // staging region now dead

    // ---- kzH reduction via LDS sum buffer [32 tok][260] ----
    if (kzH == 1 && kzL == 0) {
        #pragma unroll
        for (int i = 0; i < 8; ++i)
            #pragma unroll
            for (int j = 0; j < 8; ++j)
                smem[SB_OFF + (tg * 8 + i) * SB_LDW + hg + 32 * j] = acc[i][j];
    }
    // stage Wg concurrently (region disjoint from sumbuf)
    {
        const int fi = WG_OFF + t * 8;
        *(float4*)&smem[fi]     = *(const float4*)&Wg[t * 8];
        *(float4*)&smem[fi + 4] = *(const float4*)&Wg[t * 8 + 4];
    }
    if (t < 16)  smem[LB_OFF + t] = 0.f;
    if (t == 16) smem[Z_OFF] = 0.f;
    __syncthreads();
    if (kzH == 0 && kzL == 0) {
        #pragma unroll
        for (int i = 0; i < 8; ++i)
            #pragma unroll
            for (int j = 0; j < 8; ++j)
                smem[SB_OFF + (tg * 8 + i) * SB_LDW + hg + 32 * j] += acc[i][j];
    }
    __syncthreads();

    // ---- post phase: 1 token per thread-slot (tx = t&15, tokl = t>>4) ----
    const int tx   = t & 15;
    const int tokl = t >> 4;                    // 0..31
    const int tok  = tok0 + tokl;

    float pr[16];
    #pragma unroll
    for (int j = 0; j < 16; ++j)
        pr[j] = smem[SB_OFF + tokl * SB_LDW + tx + 16 * j];

    float lnw[16], lnb[16];
    #pragma unroll
    for (int j = 0; j < 16; ++j) {
        lnw[j] = lnw_g[tx + 16 * j];
        lnb[j] = lnb_g[tx + 16 * j];
    }
    const float temp = fabsf(temp_g[0]) + 1e-6f;

    // mean / variance over H (16-lane butterfly)
    float s = 0.f;
    #pragma unroll
    for (int j = 0; j < 16; ++j) s += pr[j];
    s += __shfl_xor(s, 1); s += __shfl_xor(s, 2);
    s += __shfl_xor(s, 4); s += __shfl_xor(s, 8);
    const float mu = s * (1.f / 256.f);
    float v = 0.f;
    #pragma unroll
    for (int j = 0; j < 16; ++j) { const float d = pr[j] - mu; v = fmaf(d, d, v); }
    v += __shfl_xor(v, 1); v += __shfl_xor(v, 2);
    v += __shfl_xor(v, 4); v += __shfl_xor(v, 8);
    const float rstd = 1.0f / sqrtf(v * (1.f / 256.f) + 1e-5f);

    float n[16];
    #pragma unroll
    for (int j = 0; j < 16; ++j)
        n[j] = fmaf((pr[j] - mu) * rstd, lnw[j], lnb[j]);

    // logits partials over this lane's 16 h-columns
    float p[16];
    #pragma unroll
    for (int e = 0; e < 16; ++e) p[e] = 0.f;
    #pragma unroll
    for (int j = 0; j < 16; ++j) {
        const float nv = n[j];
        const int  h   = tx + 16 * j;
        #pragma unroll
        for (int e = 0; e < 16; ++e)
            p[e] = fmaf(nv, smem[WG_OFF + e * H + h], p[e]);
    }
    #pragma unroll
    for (int m = 1; m < 16; m <<= 1)
        #pragma unroll
        for (int e = 0; e < 16; ++e) p[e] += __shfl_xor(p[e], m);
    #pragma unroll
    for (int e = 0; e < 16; ++e) p[e] = p[e] / temp;

    float myz = 0.f;
    if (tx == 0) {
        #pragma unroll
        for (int e = 0; e < 16; ++e) myz = fmaf(p[e], p[e], myz);
    }

    // softmax (stable)
    float mx = p[0];
    #pragma unroll
    for (int e = 1; e < 16; ++e) mx = fmaxf(mx, p[e]);
    float w[16]; float sw = 0.f;
    #pragma unroll
    for (int e = 0; e < 16; ++e) { w[e] = expf(p[e] - mx); sw += w[e]; }
    #pragma unroll
    for (int e = 0; e < 16; ++e) w[e] = w[e] / sw;

    // top-2 (ties -> lower index)
    float w1 = -1.f; int i1 = 0; float w2 = -1.f; int i2 = 0;
    #pragma unroll
    for (int e = 0; e < 16; ++e) {
        const float we = w[e];
        if (we > w1)      { w2 = w1; i2 = i1; w1 = we; i1 = e; }
        else if (we > w2) { w2 = we; i2 = e; }
    }
    const float rs = 1.f / (w1 + w2 + 1e-6f);
    out_rw  [(size_t)tok * E + tx] = w[tx];
    out_disp[(size_t)tok * E + tx] = (tx == i1) ? w1 * rs : (tx == i2 ? w2 * rs : 0.f);

    atomicAdd(&smem[LB_OFF + tx], w[tx]);
    if (tx == 0) atomicAdd(&smem[Z_OFF], myz);
    __syncthreads();
    if (t < 16)  ws_part[blockIdx.x * WS_STRIDE + t]  = smem[LB_OFF + t];
    if (t == 16) ws_part[blockIdx.x * WS_STRIDE + 16] = smem[Z_OFF];
}

__global__ void router_final(const float* __restrict__ ws_part,
                             float* __restrict__ out_loss, int nblocks, int T)
{
    const int l = threadIdx.x;   // 64 threads
    float lb[16]; float z = 0.f;
    #pragma unroll
    for (int e = 0; e < 16; ++e) lb[e] = 0.f;
    for (int b = l; b < nblocks; b += 64) {
        #pragma unroll
        for (int e = 0; e < 16; ++e) lb[e] += ws_part[b * WS_STRIDE + e];
        z += ws_part[b * WS_STRIDE + 16];
    }
    #pragma unroll
    for (int m = 1; m < 64; m <<= 1) {
        #pragma unroll
        for (int e = 0; e < 16; ++e) lb[e] += __shfl_xor(lb[e], m);
        z += __shfl_xor(z, m);
    }
    if (l == 0) {
        const float zloss = z / (float)(T * 16);
        const float ideal = 1.f / 16.f;
        float lbl = 0.f;
        #pragma unroll
        for (int e = 0; e < 16; ++e) {
            const float a = lb[e] / (float)T;
            lbl += ideal * (logf(ideal) - logf(a));
        }
        lbl *= (1.f / 16.f);
        out_loss[0] = 0.005f * zloss + 0.005f * lbl;
    }
}

extern "C" void kernel_launch(void* const* d_in, const int* in_sizes, int n_in,
                              void* d_out, int out_size, void* d_ws, size_t ws_size,
                              hipStream_t stream)
{
    const float* x    = (const float*)d_in[0];
    const float* Wp   = (const float*)d_in[1];
    const float* Wg   = (const float*)d_in[2];
    const float* lnw  = (const float*)d_in[3];
    const float* lnb  = (const float*)d_in[4];
    const float* temp = (const float*)d_in[5];
    const int T = in_sizes[0] / D;           // 16384
    float* out      = (float*)d_out;
    float* out_rw   = out;
    float* out_disp = out + (size_t)T * E;
    float* out_loss = out + (size_t)2 * T * E;
    float* ws_part  = (float*)d_ws;
    const int nblocks = T / TMB;             // 512

    hipLaunchKernelGGL(router_main, dim3(nblocks), dim3(THREADS), 0, stream,
                       x, Wp, Wg, lnw, lnb, temp, out_rw, out_disp, ws_part);
    hipLaunchKernelGGL(router_final, dim3(1), dim3(64), 0, stream,
                       ws_part, out_loss, nblocks, T);
}

// Round 6
// 624.325 us; speedup vs baseline: 2.3622x; 2.3622x over previous
//
#include <hip/hip_runtime.h>
#include <hip/hip_bf16.h>
#include <math.h>

#define D 2048
#define H 256
#define E 16
#define TMB 32                    // tokens per block
#define BK 32                     // k-chunk
#define LDW 36                    // Wp staging row stride (floats); 144B rows, 16B-aligned
#define THREADS 256
#define NCH (D / BK)              // 64
#define SB_LDW 260
#define SB_OFF 0                  // proj buffer [32][260] (aliases staging after GEMM)
#define WG_OFF (TMB * SB_LDW)     // 8320
#define LB_OFF (WG_OFF + E * H)   // 12416
#define Z_OFF  (LB_OFF + 16)      // 12432
#define SMEM_FLOATS 12448         // 49.8 KB (staging region [0,9216) fits inside)
#define WS_STRIDE 20

__global__ __launch_bounds__(THREADS)
void router_main(const float* __restrict__ x, const float* __restrict__ Wp,
                 const float* __restrict__ Wg, const float* __restrict__ lnw_g,
                 const float* __restrict__ lnb_g, const float* __restrict__ temp_g,
                 float* __restrict__ out_rw, float* __restrict__ out_disp,
                 float* __restrict__ ws_part)
{
    __shared__ __align__(16) float smem[SMEM_FLOATS];
    const int t  = threadIdx.x;
    const int l  = t & 63;                                   // lane
    // wave-uniform ids, FORCED uniform so x-loads scalarize to s_load:
    const int tw = __builtin_amdgcn_readfirstlane((t >> 6) & 1);  // token-group
    const int hw = __builtin_amdgcn_readfirstlane(t >> 7);        // h-half
    const int r8 = t >> 3;          // staging row 0..31
    const int c8 = (t & 7) << 2;    // staging col (floats)
    const int tok0 = blockIdx.x * TMB;
    const float* xrow = &x[(size_t)(tok0 + tw * 16) * D];    // wave's 16 token rows

    float acc[16][2];
    #pragma unroll
    for (int i = 0; i < 16; ++i) { acc[i][0] = 0.f; acc[i][1] = 0.f; }

    // Wp register prefetch (L2-resident: Wp = 2MB, re-read per block)
    float4 wst[8];
    auto ISSUE = [&](int k0) {
        #pragma unroll
        for (int p = 0; p < 8; ++p)
            wst[p] = *(const float4*)&Wp[(size_t)(p * 32 + r8) * D + k0 + c8];
    };
    ISSUE(0);

    const float* wrow0 = &smem[(hw * 128 + l) * LDW];        // hi=0 row
    const float* wrow1 = &smem[(hw * 128 + 64 + l) * LDW];   // hi=1 row

    for (int c = 0; c < NCH; ++c) {
        const int k0 = c * BK;
        __syncthreads();                       // prior chunk's LDS reads done
        #pragma unroll
        for (int p = 0; p < 8; ++p)
            *(float4*)&smem[(p * 32 + r8) * LDW + c8] = wst[p];
        __syncthreads();
        if (c + 1 < NCH) ISSUE(k0 + BK);       // prefetch next Wp tile under compute

        #pragma unroll
        for (int kk = 0; kk < 8; ++kk) {       // 4 k per step
            const float4 wa = *(const float4*)&wrow0[kk * 4];
            const float4 wb = *(const float4*)&wrow1[kk * 4];
            #pragma unroll
            for (int i = 0; i < 16; ++i) {
                // wave-uniform address -> s_load (x lives in SGPRs, broadcast)
                const float4 xv = *(const float4*)&xrow[(size_t)i * D + k0 + kk * 4];
                acc[i][0] = fmaf(xv.x, wa.x, acc[i][0]);
                acc[i][0] = fmaf(xv.y, wa.y, acc[i][0]);
                acc[i][0] = fmaf(xv.z, wa.z, acc[i][0]);
                acc[i][0] = fmaf(xv.w, wa.w, acc[i][0]);
                acc[i][1] = fmaf(xv.x, wb.x, acc[i][1]);
                acc[i][1] = fmaf(xv.y, wb.y, acc[i][1]);
                acc[i][1] = fmaf(xv.z, wb.z, acc[i][1]);
                acc[i][1] = fmaf(xv.w, wb.w, acc[i][1]);
            }
        }
    }

    // ---- dump proj to LDS [32][260]; stage Wg; zero reducers ----
    __syncthreads();                           // staging region now dead
    #pragma unroll
    for (int i = 0; i < 16; ++i) {
        smem[SB_OFF + (tw * 16 + i) * SB_LDW + hw * 128 + l]      = acc[i][0];
        smem[SB_OFF + (tw * 16 + i) * SB_LDW + hw * 128 + 64 + l] = acc[i][1];
    }
    #pragma unroll
    for (int p = 0; p < 4; ++p) {
        const int fi = (p * 256 + t) * 4;      // 1024 float4 total
        *(float4*)&smem[WG_OFF + fi] = *(const float4*)&Wg[fi];
    }
    if (t < 16)  smem[LB_OFF + t] = 0.f;
    if (t == 16) smem[Z_OFF] = 0.f;
    __syncthreads();

    // ---- post phase: (tx, tokl) slots; 2 tokens per thread ----
    const int tx = t & 15;
    float lnw[16], lnb[16];
    #pragma unroll
    for (int j = 0; j < 16; ++j) {
        lnw[j] = lnw_g[tx + 16 * j];
        lnb[j] = lnb_g[tx + 16 * j];
    }
    const float temp = fabsf(temp_g[0]) + 1e-6f;

    float mylb = 0.f, myz = 0.f;

    #pragma unroll
    for (int i01 = 0; i01 < 2; ++i01) {
        const int tokl = (t >> 4) + 16 * i01;  // 0..31
        const int tok  = tok0 + tokl;

        float pr[16];
        #pragma unroll
        for (int j = 0; j < 16; ++j)
            pr[j] = smem[SB_OFF + tokl * SB_LDW + tx + 16 * j];

        // mean / variance over H (16-lane butterfly)
        float s = 0.f;
        #pragma unroll
        for (int j = 0; j < 16; ++j) s += pr[j];
        s += __shfl_xor(s, 1); s += __shfl_xor(s, 2);
        s += __shfl_xor(s, 4); s += __shfl_xor(s, 8);
        const float mu = s * (1.f / 256.f);
        float v = 0.f;
        #pragma unroll
        for (int j = 0; j < 16; ++j) { const float d = pr[j] - mu; v = fmaf(d, d, v); }
        v += __shfl_xor(v, 1); v += __shfl_xor(v, 2);
        v += __shfl_xor(v, 4); v += __shfl_xor(v, 8);
        const float rstd = 1.0f / sqrtf(v * (1.f / 256.f) + 1e-5f);

        float n[16];
        #pragma unroll
        for (int j = 0; j < 16; ++j)
            n[j] = fmaf((pr[j] - mu) * rstd, lnw[j], lnb[j]);

        // logits partials over this lane's 16 h-columns
        float p[16];
        #pragma unroll
        for (int e = 0; e < 16; ++e) p[e] = 0.f;
        #pragma unroll
        for (int j = 0; j < 16; ++j) {
            const float nv = n[j];
            const int  h   = tx + 16 * j;
            #pragma unroll
            for (int e = 0; e < 16; ++e)
                p[e] = fmaf(nv, smem[WG_OFF + e * H + h], p[e]);
        }
        #pragma unroll
        for (int m = 1; m < 16; m <<= 1)
            #pragma unroll
            for (int e = 0; e < 16; ++e) p[e] += __shfl_xor(p[e], m);
        #pragma unroll
        for (int e = 0; e < 16; ++e) p[e] = p[e] / temp;

        if (tx == 0) {
            #pragma unroll
            for (int e = 0; e < 16; ++e) myz = fmaf(p[e], p[e], myz);
        }

        // softmax (stable)
        float mx = p[0];
        #pragma unroll
        for (int e = 1; e < 16; ++e) mx = fmaxf(mx, p[e]);
        float w[16]; float sw = 0.f;
        #pragma unroll
        for (int e = 0; e < 16; ++e) { w[e] = expf(p[e] - mx); sw += w[e]; }
        #pragma unroll
        for (int e = 0; e < 16; ++e) w[e] = w[e] / sw;
        mylb += w[tx];

        // top-2 (ties -> lower index)
        float w1 = -1.f; int i1 = 0; float w2 = -1.f; int i2 = 0;
        #pragma unroll
        for (int e = 0; e < 16; ++e) {
            const float we = w[e];
            if (we > w1)      { w2 = w1; i2 = i1; w1 = we; i1 = e; }
            else if (we > w2) { w2 = we; i2 = e; }
        }
        const float rs = 1.f / (w1 + w2 + 1e-6f);
        out_rw  [(size_t)tok * E + tx] = w[tx];
        out_disp[(size_t)tok * E + tx] = (tx == i1) ? w1 * rs : (tx == i2 ? w2 * rs : 0.f);
    }

    atomicAdd(&smem[LB_OFF + tx], mylb);
    if (tx == 0) atomicAdd(&smem[Z_OFF], myz);
    __syncthreads();
    if (t < 16)  ws_part[blockIdx.x * WS_STRIDE + t]  = smem[LB_OFF + t];
    if (t == 16) ws_part[blockIdx.x * WS_STRIDE + 16] = smem[Z_OFF];
}

__global__ void router_final(const float* __restrict__ ws_part,
                             float* __restrict__ out_loss, int nblocks, int T)
{
    const int l = threadIdx.x;   // 64 threads
    float lb[16]; float z = 0.f;
    #pragma unroll
    for (int e = 0; e < 16; ++e) lb[e] = 0.f;
    for (int b = l; b < nblocks; b += 64) {
        #pragma unroll
        for (int e = 0; e < 16; ++e) lb[e] += ws_part[b * WS_STRIDE + e];
        z += ws_part[b * WS_STRIDE + 16];
    }
    #pragma unroll
    for (int m = 1; m < 64; m <<= 1) {
        #pragma unroll
        for (int e = 0; e < 16; ++e) lb[e] += __shfl_xor(lb[e], m);
        z += __shfl_xor(z, m);
    }
    if (l == 0) {
        const float zloss = z / (float)(T * 16);
        const float ideal = 1.f / 16.f;
        float lbl = 0.f;
        #pragma unroll
        for (int e = 0; e < 16; ++e) {
            const float a = lb[e] / (float)T;
            lbl += ideal * (logf(ideal) - logf(a));
        }
        lbl *= (1.f / 16.f);
        out_loss[0] = 0.005f * zloss + 0.005f * lbl;
    }
}

extern "C" void kernel_launch(void* const* d_in, const int* in_sizes, int n_in,
                              void* d_out, int out_size, void* d_ws, size_t ws_size,
                              hipStream_t stream)
{
    const float* x    = (const float*)d_in[0];
    const float* Wp   = (const float*)d_in[1];
    const float* Wg   = (const float*)d_in[2];
    const float* lnw  = (const float*)d_in[3];
    const float* lnb  = (const float*)d_in[4];
    const float* temp = (const float*)d_in[5];
    const int T = in_sizes[0] / D;           // 16384
    float* out      = (float*)d_out;
    float* out_rw   = out;
    float* out_disp = out + (size_t)T * E;
    float* out_loss = out + (size_t)2 * T * E;
    float* ws_part  = (float*)d_ws;
    const int nblocks = T / TMB;             // 512

    hipLaunchKernelGGL(router_main, dim3(nblocks), dim3(THREADS), 0, stream,
                       x, Wp, Wg, lnw, lnb, temp, out_rw, out_disp, ws_part);
    hipLaunchKernelGGL(router_final, dim3(1), dim3(64), 0, stream,
                       ws_part, out_loss, nblocks, T);
}

// Round 7
// 300.543 us; speedup vs baseline: 4.9071x; 2.0773x over previous
//
#include <hip/hip_runtime.h>
#include <hip/hip_bf16.h>
#include <math.h>

#define D 2048
#define H 256
#define E 16
#define TMB 32                 // tokens per block
#define BK 16                  // k-chunk; each ku-lane owns a 4-k window
#define NCH (D / BK)           // 128
#define LDK 20                 // Wp LDS row stride (floats): (5*tx+ku)&7 uniform banks
#define LDXK 16                // x LDS row stride
#define WP_OFF 0               // [256][20] = 5120 floats
#define X_OFF  5120            // [32][16]  = 512   (staging ends 5632)
#define SB_LDW 260
#define SB_OFF 0               // post proj buffer [32][260] = 8320 (aliases staging)
#define WG_OFF 8320            // [16][256] = 4096
#define LB_OFF 12416
#define Z_OFF  12432
#define SMEM_FLOATS 12448      // 49.8 KB/block -> 2 blocks/CU
#define THREADS 512
#define WS_STRIDE 20

__global__ __launch_bounds__(THREADS)
void router_main(const float* __restrict__ x, const float* __restrict__ Wp,
                 const float* __restrict__ Wg, const float* __restrict__ lnw_g,
                 const float* __restrict__ lnb_g, const float* __restrict__ temp_g,
                 float* __restrict__ out_rw, float* __restrict__ out_disp,
                 float* __restrict__ ws_part)
{
    __shared__ __align__(16) float smem[SMEM_FLOATS];
    const int t  = threadIdx.x;
    const int tx = t & 15;           // h-lane (lane bits 0-3)
    const int ku = (t >> 4) & 3;     // private 4-k window (lane bits 4-5)
    const int tb = (t >> 6) & 3;     // token octet (wave bits)
    const int hb = t >> 8;           // h-half (wave bit)
    const int tok0 = blockIdx.x * TMB;

    float acc[8][8];
    #pragma unroll
    for (int i = 0; i < 8; ++i)
        #pragma unroll
        for (int j = 0; j < 8; ++j) acc[i][j] = 0.f;

    // staging registers (transient): Wp 8 floats/thread, x 1 f4 for t<128
    const int wrow = t >> 1;              // 0..255
    const int wcol = (t & 1) * 8;         // 0 or 8
    const int xrw  = t >> 2;              // 0..127
    const int xcl  = (t & 3) * 4;
    float4 wpr0, wpr1, xr;
    auto ISSUE = [&](int k0) {
        wpr0 = *(const float4*)&Wp[(size_t)wrow * D + k0 + wcol];
        wpr1 = *(const float4*)&Wp[(size_t)wrow * D + k0 + wcol + 4];
        if (t < 128) xr = *(const float4*)&x[(size_t)(tok0 + xrw) * D + k0 + xcl];
    };
    ISSUE(0);

    const float* wbase = &smem[WP_OFF + (hb * 128 + tx) * LDK + ku * 4];
    const float* xbase = &smem[X_OFF + (tb * 8) * LDXK + ku * 4];

    for (int c = 0; c < NCH; ++c) {
        __syncthreads();                     // prior chunk's reads done
        *(float4*)&smem[WP_OFF + wrow * LDK + wcol]     = wpr0;
        *(float4*)&smem[WP_OFF + wrow * LDK + wcol + 4] = wpr1;
        if (t < 128) *(float4*)&smem[X_OFF + xrw * LDXK + xcl] = xr;
        __syncthreads();
        if (c + 1 < NCH) ISSUE((c + 1) * BK);   // prefetch under compute

        float4 xa[8];
        #pragma unroll
        for (int i = 0; i < 8; ++i)
            xa[i] = *(const float4*)&xbase[i * LDXK];    // lane's 4-k window, 8 tokens
        #pragma unroll
        for (int j = 0; j < 8; ++j) {
            // 64-distinct-address ds_read_b128: 16 tx-rows x 4 ku-windows
            const float4 wv = *(const float4*)&wbase[j * 16 * LDK];
            #pragma unroll
            for (int i = 0; i < 8; ++i) {
                acc[i][j] = fmaf(xa[i].x, wv.x, acc[i][j]);
                acc[i][j] = fmaf(xa[i].y, wv.y, acc[i][j]);
                acc[i][j] = fmaf(xa[i].z, wv.z, acc[i][j]);
                acc[i][j] = fmaf(xa[i].w, wv.w, acc[i][j]);
            }
        }
    }

    // ---- k-window reduction: in-wave butterflies over lane bits 4,5 ----
    #pragma unroll
    for (int i = 0; i < 8; ++i)
        #pragma unroll
        for (int j = 0; j < 8; ++j) {
            acc[i][j] += __shfl_xor(acc[i][j], 16);
            acc[i][j] += __shfl_xor(acc[i][j], 32);
        }

    __syncthreads();                          // staging region now dead

    // ---- dump proj to LDS [32][260]; stage Wg; zero reducers ----
    if (ku == 0) {
        #pragma unroll
        for (int i = 0; i < 8; ++i)
            #pragma unroll
            for (int j = 0; j < 8; ++j)
                smem[SB_OFF + (tb * 8 + i) * SB_LDW + hb * 128 + tx + 16 * j] = acc[i][j];
    }
    {
        const int fi = t * 8;                 // 512 thr x 8 floats = 4096
        *(float4*)&smem[WG_OFF + fi]     = *(const float4*)&Wg[fi];
        *(float4*)&smem[WG_OFF + fi + 4] = *(const float4*)&Wg[fi + 4];
    }
    if (t < 16)  smem[LB_OFF + t] = 0.f;
    if (t == 16) smem[Z_OFF] = 0.f;
    __syncthreads();

    // ---- post phase: one token per (tx, tokl) slot ----
    const int ptx  = t & 15;
    const int tokl = t >> 4;                  // 0..31
    const int tok  = tok0 + tokl;

    float pr[16];
    #pragma unroll
    for (int j = 0; j < 16; ++j)
        pr[j] = smem[SB_OFF + tokl * SB_LDW + ptx + 16 * j];

    float lnw[16], lnb[16];
    #pragma unroll
    for (int j = 0; j < 16; ++j) {
        lnw[j] = lnw_g[ptx + 16 * j];
        lnb[j] = lnb_g[ptx + 16 * j];
    }
    const float temp = fabsf(temp_g[0]) + 1e-6f;

    // mean / variance over H (16-lane butterfly)
    float s = 0.f;
    #pragma unroll
    for (int j = 0; j < 16; ++j) s += pr[j];
    s += __shfl_xor(s, 1); s += __shfl_xor(s, 2);
    s += __shfl_xor(s, 4); s += __shfl_xor(s, 8);
    const float mu = s * (1.f / 256.f);
    float v = 0.f;
    #pragma unroll
    for (int j = 0; j < 16; ++j) { const float d = pr[j] - mu; v = fmaf(d, d, v); }
    v += __shfl_xor(v, 1); v += __shfl_xor(v, 2);
    v += __shfl_xor(v, 4); v += __shfl_xor(v, 8);
    const float rstd = 1.0f / sqrtf(v * (1.f / 256.f) + 1e-5f);

    float n[16];
    #pragma unroll
    for (int j = 0; j < 16; ++j)
        n[j] = fmaf((pr[j] - mu) * rstd, lnw[j], lnb[j]);

    float p[16];
    #pragma unroll
    for (int e = 0; e < 16; ++e) p[e] = 0.f;
    #pragma unroll
    for (int j = 0; j < 16; ++j) {
        const float nv = n[j];
        const int  h   = ptx + 16 * j;
        #pragma unroll
        for (int e = 0; e < 16; ++e)
            p[e] = fmaf(nv, smem[WG_OFF + e * H + h], p[e]);
    }
    #pragma unroll
    for (int m = 1; m < 16; m <<= 1)
        #pragma unroll
        for (int e = 0; e < 16; ++e) p[e] += __shfl_xor(p[e], m);
    #pragma unroll
    for (int e = 0; e < 16; ++e) p[e] = p[e] / temp;

    float myz = 0.f;
    if (ptx == 0) {
        #pragma unroll
        for (int e = 0; e < 16; ++e) myz = fmaf(p[e], p[e], myz);
    }

    // softmax (stable)
    float mx = p[0];
    #pragma unroll
    for (int e = 1; e < 16; ++e) mx = fmaxf(mx, p[e]);
    float w[16]; float sw = 0.f;
    #pragma unroll
    for (int e = 0; e < 16; ++e) { w[e] = expf(p[e] - mx); sw += w[e]; }
    #pragma unroll
    for (int e = 0; e < 16; ++e) w[e] = w[e] / sw;

    // top-2 (ties -> lower index)
    float w1 = -1.f; int i1 = 0; float w2 = -1.f; int i2 = 0;
    #pragma unroll
    for (int e = 0; e < 16; ++e) {
        const float we = w[e];
        if (we > w1)      { w2 = w1; i2 = i1; w1 = we; i1 = e; }
        else if (we > w2) { w2 = we; i2 = e; }
    }
    const float rs = 1.f / (w1 + w2 + 1e-6f);
    out_rw  [(size_t)tok * E + ptx] = w[ptx];
    out_disp[(size_t)tok * E + ptx] = (ptx == i1) ? w1 * rs : (ptx == i2 ? w2 * rs : 0.f);

    atomicAdd(&smem[LB_OFF + ptx], w[ptx]);
    if (ptx == 0) atomicAdd(&smem[Z_OFF], myz);
    __syncthreads();
    if (t < 16)  ws_part[blockIdx.x * WS_STRIDE + t]  = smem[LB_OFF + t];
    if (t == 16) ws_part[blockIdx.x * WS_STRIDE + 16] = smem[Z_OFF];
}

__global__ void router_final(const float* __restrict__ ws_part,
                             float* __restrict__ out_loss, int nblocks, int T)
{
    const int l = threadIdx.x;   // 64 threads
    float lb[16]; float z = 0.f;
    #pragma unroll
    for (int e = 0; e < 16; ++e) lb[e] = 0.f;
    for (int b = l; b < nblocks; b += 64) {
        #pragma unroll
        for (int e = 0; e < 16; ++e) lb[e] += ws_part[b * WS_STRIDE + e];
        z += ws_part[b * WS_STRIDE + 16];
    }
    #pragma unroll
    for (int m = 1; m < 64; m <<= 1) {
        #pragma unroll
        for (int e = 0; e < 16; ++e) lb[e] += __shfl_xor(lb[e], m);
        z += __shfl_xor(z, m);
    }
    if (l == 0) {
        const float zloss = z / (float)(T * 16);
        const float ideal = 1.f / 16.f;
        float lbl = 0.f;
        #pragma unroll
        for (int e = 0; e < 16; ++e) {
            const float a = lb[e] / (float)T;
            lbl += ideal * (logf(ideal) - logf(a));
        }
        lbl *= (1.f / 16.f);
        out_loss[0] = 0.005f * zloss + 0.005f * lbl;
    }
}

extern "C" void kernel_launch(void* const* d_in, const int* in_sizes, int n_in,
                              void* d_out, int out_size, void* d_ws, size_t ws_size,
                              hipStream_t stream)
{
    const float* x    = (const float*)d_in[0];
    const float* Wp   = (const float*)d_in[1];
    const float* Wg   = (const float*)d_in[2];
    const float* lnw  = (const float*)d_in[3];
    const float* lnb  = (const float*)d_in[4];
    const float* temp = (const float*)d_in[5];
    const int T = in_sizes[0] / D;           // 16384
    float* out      = (float*)d_out;
    float* out_rw   = out;
    float* out_disp = out + (size_t)T * E;
    float* out_loss = out + (size_t)2 * T * E;
    float* ws_part  = (float*)d_ws;
    const int nblocks = T / TMB;             // 512

    hipLaunchKernelGGL(router_main, dim3(nblocks), dim3(THREADS), 0, stream,
                       x, Wp, Wg, lnw, lnb, temp, out_rw, out_disp, ws_part);
    hipLaunchKernelGGL(router_final, dim3(1), dim3(64), 0, stream,
                       ws_part, out_loss, nblocks, T);
}

// Round 8
// 294.918 us; speedup vs baseline: 5.0007x; 1.0191x over previous
//
#include <hip/hip_runtime.h>
#include <hip/hip_bf16.h>
#include <math.h>

#define D 2048
#define H 256
#define E 16
#define TMB 64                 // tokens per block
#define BK 16                  // k-chunk; each ku-lane owns a 4-k window
#define NCH (D / BK)           // 128
#define LDK 20                 // Wp LDS row stride (floats): (5tx+ku)&7 uniform bank groups
#define WP_OFF 0               // [256][20] = 5120 floats
#define X_OFF 5120             // [64][16]  = 1024  (staging ends 6144)
#define SB_LDW 257             // proj buffer stride: <=2-way conflicts on strided reads
#define SB_OFF 0               // [32][257] = 8224 (aliases staging during post)
#define WG_OFF 8224            // [16][256] = 4096 (persistent, staged at kernel start)
#define LB_OFF 12320
#define Z_OFF  12336
#define SMEM_FLOATS 12352      // 49.4 KB -> fits static-LDS limit, 1 block/CU
#define THREADS 1024
#define WS_STRIDE 20

__global__ __launch_bounds__(THREADS, 4)
void router_main(const float* __restrict__ x, const float* __restrict__ Wp,
                 const float* __restrict__ Wg, const float* __restrict__ lnw_g,
                 const float* __restrict__ lnb_g, const float* __restrict__ temp_g,
                 float* __restrict__ out_rw, float* __restrict__ out_disp,
                 float* __restrict__ ws_part)
{
    __shared__ __align__(16) float smem[SMEM_FLOATS];
    const int t  = threadIdx.x;
    const int tx = t & 15;           // h-lane (lane bits 0-3)
    const int ku = (t >> 4) & 3;     // private 4-k window (lane bits 4-5)
    const int wv = t >> 6;           // wave 0..15
    const int tb = wv & 7;           // token octet (8 tokens)
    const int hb = wv >> 3;          // h-half
    const int wrow = t >> 2;         // staging row 0..255
    const int wcol = (t & 3) << 2;   // staging col (floats)
    const int tok0 = blockIdx.x * TMB;

    // stage Wg once into persistent region [8224, 12320)
    *(float4*)&smem[WG_OFF + 4 * t] = *(const float4*)&Wg[4 * t];

    float acc[8][8];
    #pragma unroll
    for (int i = 0; i < 8; ++i)
        #pragma unroll
        for (int j = 0; j < 8; ++j) acc[i][j] = 0.f;

    float4 wpr, xr;
    auto ISSUE = [&](int k0) {
        wpr = *(const float4*)&Wp[(size_t)wrow * D + k0 + wcol];
        if (t < 256) xr = *(const float4*)&x[(size_t)(tok0 + wrow) * D + k0 + wcol];
    };
    ISSUE(0);

    const float* wbase = &smem[WP_OFF + (hb * 128 + tx) * LDK + ku * 4];
    const float* xbase = &smem[X_OFF + tb * 128 + ku * 4];

    for (int c = 0; c < NCH; ++c) {
        __syncthreads();                     // prior chunk's reads done
        *(float4*)&smem[WP_OFF + wrow * LDK + wcol] = wpr;
        if (t < 256) *(float4*)&smem[X_OFF + wrow * 16 + wcol] = xr;
        __syncthreads();
        if (c + 1 < NCH) ISSUE((c + 1) * BK);   // prefetch under compute

        float4 xa[8];
        #pragma unroll
        for (int i = 0; i < 8; ++i)
            xa[i] = *(const float4*)&xbase[i * 16];   // broadcast reads
        #pragma unroll
        for (int j = 0; j < 8; ++j) {
            const float4 wvv = *(const float4*)&wbase[j * 16 * LDK];  // 64-distinct b128
            #pragma unroll
            for (int i = 0; i < 8; ++i) {
                acc[i][j] = fmaf(xa[i].x, wvv.x, acc[i][j]);
                acc[i][j] = fmaf(xa[i].y, wvv.y, acc[i][j]);
                acc[i][j] = fmaf(xa[i].z, wvv.z, acc[i][j]);
                acc[i][j] = fmaf(xa[i].w, wvv.w, acc[i][j]);
            }
        }
    }

    // ---- k-window reduction: in-wave butterflies over lane bits 4,5 ----
    #pragma unroll
    for (int i = 0; i < 8; ++i)
        #pragma unroll
        for (int j = 0; j < 8; ++j) {
            acc[i][j] += __shfl_xor(acc[i][j], 16);
            acc[i][j] += __shfl_xor(acc[i][j], 32);
        }

    __syncthreads();                          // staging region now dead

    const float temp = fabsf(temp_g[0]) + 1e-6f;
    float lnw[16], lnb[16];
    if (t < 512) {
        #pragma unroll
        for (int j = 0; j < 16; ++j) {
            lnw[j] = lnw_g[(t & 15) + 16 * j];
            lnb[j] = lnb_g[(t & 15) + 16 * j];
        }
    }
    float mylb = 0.f, myz = 0.f;

    // ---------- two post passes over 32-token halves ----------
    #pragma unroll
    for (int pass = 0; pass < 2; ++pass) {
        // dump this half's proj into SB [32][257]
        if (ku == 0 && (tb >> 2) == pass) {
            const int rb = (tb & 3) * 8;
            #pragma unroll
            for (int i = 0; i < 8; ++i)
                #pragma unroll
                for (int j = 0; j < 8; ++j)
                    smem[SB_OFF + (rb + i) * SB_LDW + hb * 128 + tx + 16 * j] = acc[i][j];
        }
        if (pass == 0) {
            if (t < 16)  smem[LB_OFF + t] = 0.f;
            if (t == 16) smem[Z_OFF] = 0.f;
        }
        __syncthreads();

        if (t < 512) {
            const int ptx  = t & 15;
            const int tokl = t >> 4;                  // 0..31
            const int tok  = tok0 + pass * 32 + tokl;

            float pr[16];
            #pragma unroll
            for (int j = 0; j < 16; ++j)
                pr[j] = smem[SB_OFF + tokl * SB_LDW + ptx + 16 * j];

            // mean / variance over H (16-lane butterfly)
            float s = 0.f;
            #pragma unroll
            for (int j = 0; j < 16; ++j) s += pr[j];
            s += __shfl_xor(s, 1); s += __shfl_xor(s, 2);
            s += __shfl_xor(s, 4); s += __shfl_xor(s, 8);
            const float mu = s * (1.f / 256.f);
            float v = 0.f;
            #pragma unroll
            for (int j = 0; j < 16; ++j) { const float d = pr[j] - mu; v = fmaf(d, d, v); }
            v += __shfl_xor(v, 1); v += __shfl_xor(v, 2);
            v += __shfl_xor(v, 4); v += __shfl_xor(v, 8);
            const float rstd = 1.0f / sqrtf(v * (1.f / 256.f) + 1e-5f);

            float n[16];
            #pragma unroll
            for (int j = 0; j < 16; ++j)
                n[j] = fmaf((pr[j] - mu) * rstd, lnw[j], lnb[j]);

            float p[16];
            #pragma unroll
            for (int e = 0; e < 16; ++e) p[e] = 0.f;
            #pragma unroll
            for (int j = 0; j < 16; ++j) {
                const float nv = n[j];
                const int  h   = ptx + 16 * j;
                #pragma unroll
                for (int e = 0; e < 16; ++e)
                    p[e] = fmaf(nv, smem[WG_OFF + e * H + h], p[e]);
            }
            #pragma unroll
            for (int m = 1; m < 16; m <<= 1)
                #pragma unroll
                for (int e = 0; e < 16; ++e) p[e] += __shfl_xor(p[e], m);
            #pragma unroll
            for (int e = 0; e < 16; ++e) p[e] = p[e] / temp;

            if (ptx == 0) {
                #pragma unroll
                for (int e = 0; e < 16; ++e) myz = fmaf(p[e], p[e], myz);
            }

            // softmax (stable)
            float mx = p[0];
            #pragma unroll
            for (int e = 1; e < 16; ++e) mx = fmaxf(mx, p[e]);
            float w[16]; float sw = 0.f;
            #pragma unroll
            for (int e = 0; e < 16; ++e) { w[e] = expf(p[e] - mx); sw += w[e]; }
            #pragma unroll
            for (int e = 0; e < 16; ++e) w[e] = w[e] / sw;
            mylb += w[ptx];

            // top-2 (ties -> lower index)
            float w1 = -1.f; int i1 = 0; float w2 = -1.f; int i2 = 0;
            #pragma unroll
            for (int e = 0; e < 16; ++e) {
                const float we = w[e];
                if (we > w1)      { w2 = w1; i2 = i1; w1 = we; i1 = e; }
                else if (we > w2) { w2 = we; i2 = e; }
            }
            const float rs = 1.f / (w1 + w2 + 1e-6f);
            out_rw  [(size_t)tok * E + ptx] = w[ptx];
            out_disp[(size_t)tok * E + ptx] = (ptx == i1) ? w1 * rs : (ptx == i2 ? w2 * rs : 0.f);
        }
        __syncthreads();
    }

    // ---- loss partials: reduce 4 tokens/wave in-register, then LDS atomics ----
    if (t < 512) {
        mylb += __shfl_xor(mylb, 16); mylb += __shfl_xor(mylb, 32);
        myz  += __shfl_xor(myz, 16);  myz  += __shfl_xor(myz, 32);
        if ((t & 63) < 16) atomicAdd(&smem[LB_OFF + (t & 15)], mylb);
        if ((t & 63) == 0) atomicAdd(&smem[Z_OFF], myz);
    }
    __syncthreads();
    if (t < 16)  ws_part[blockIdx.x * WS_STRIDE + t]  = smem[LB_OFF + t];
    if (t == 16) ws_part[blockIdx.x * WS_STRIDE + 16] = smem[Z_OFF];
}

__global__ void router_final(const float* __restrict__ ws_part,
                             float* __restrict__ out_loss, int nblocks, int T)
{
    const int l = threadIdx.x;   // 64 threads
    float lb[16]; float z = 0.f;
    #pragma unroll
    for (int e = 0; e < 16; ++e) lb[e] = 0.f;
    for (int b = l; b < nblocks; b += 64) {
        #pragma unroll
        for (int e = 0; e < 16; ++e) lb[e] += ws_part[b * WS_STRIDE + e];
        z += ws_part[b * WS_STRIDE + 16];
    }
    #pragma unroll
    for (int m = 1; m < 64; m <<= 1) {
        #pragma unroll
        for (int e = 0; e < 16; ++e) lb[e] += __shfl_xor(lb[e], m);
        z += __shfl_xor(z, m);
    }
    if (l == 0) {
        const float zloss = z / (float)(T * 16);
        const float ideal = 1.f / 16.f;
        float lbl = 0.f;
        #pragma unroll
        for (int e = 0; e < 16; ++e) {
            const float a = lb[e] / (float)T;
            lbl += ideal * (logf(ideal) - logf(a));
        }
        lbl *= (1.f / 16.f);
        out_loss[0] = 0.005f * zloss + 0.005f * lbl;
    }
}

extern "C" void kernel_launch(void* const* d_in, const int* in_sizes, int n_in,
                              void* d_out, int out_size, void* d_ws, size_t ws_size,
                              hipStream_t stream)
{
    const float* x    = (const float*)d_in[0];
    const float* Wp   = (const float*)d_in[1];
    const float* Wg   = (const float*)d_in[2];
    const float* lnw  = (const float*)d_in[3];
    const float* lnb  = (const float*)d_in[4];
    const float* temp = (const float*)d_in[5];
    const int T = in_sizes[0] / D;           // 16384
    float* out      = (float*)d_out;
    float* out_rw   = out;
    float* out_disp = out + (size_t)T * E;
    float* out_loss = out + (size_t)2 * T * E;
    float* ws_part  = (float*)d_ws;
    const int nblocks = T / TMB;             // 256

    hipLaunchKernelGGL(router_main, dim3(nblocks), dim3(THREADS), 0, stream,
                       x, Wp, Wg, lnw, lnb, temp, out_rw, out_disp, ws_part);
    hipLaunchKernelGGL(router_final, dim3(1), dim3(64), 0, stream,
                       ws_part, out_loss, nblocks, T);
}

// Round 9
// 294.691 us; speedup vs baseline: 5.0045x; 1.0008x over previous
//
#include <hip/hip_runtime.h>
#include <hip/hip_bf16.h>
#include <math.h>

#define D 2048
#define H 256
#define E 16
#define TMB 64                 // tokens per block
#define BK 16                  // k-chunk; each ku-lane owns a 4-k window
#define NCH (D / BK)           // 128
#define LDK 20                 // Wp LDS row stride (floats): (5tx+ku)&7 uniform bank groups
#define WP_OFF 0               // [256][20] = 5120 floats
#define X_OFF 5120             // [64][16]  = 1024  (staging ends 6144)
#define SB_LDW 257             // proj buffer stride: <=2-way conflicts on strided reads
#define SB_OFF 0               // [32][257] = 8224 (aliases staging during post)
#define WG_OFF 8224            // [16][256] = 4096 (persistent, staged at kernel start)
#define LB_OFF 12320
#define Z_OFF  12336
#define SMEM_FLOATS 12352      // 49.4 KB -> 1 block/CU
#define THREADS 1024
#define WS_STRIDE 20

// NOTE: second launch_bounds arg empirically acts like CUDA min-BLOCKS/CU on hipcc:
// (512,4)->64reg spill (R5), (1024,4)->64reg spill (R8). Use 1 -> 128-reg cap.
__global__ __launch_bounds__(THREADS, 1)
void router_main(const float* __restrict__ x, const float* __restrict__ Wp,
                 const float* __restrict__ Wg, const float* __restrict__ lnw_g,
                 const float* __restrict__ lnb_g, const float* __restrict__ temp_g,
                 float* __restrict__ out_rw, float* __restrict__ out_disp,
                 float* __restrict__ ws_part)
{
    __shared__ __align__(16) float smem[SMEM_FLOATS];
    const int t  = threadIdx.x;
    const int tx = t & 15;           // h-lane (lane bits 0-3)
    const int ku = (t >> 4) & 3;     // private 4-k window (lane bits 4-5)
    const int wv = t >> 6;           // wave 0..15
    const int tb = wv & 7;           // token octet (8 tokens)
    const int hb = wv >> 3;          // h-half
    const int wrow = t >> 2;         // staging row 0..255
    const int wcol = (t & 3) << 2;   // staging col (floats)
    const int tok0 = blockIdx.x * TMB;

    // stage Wg once into persistent region [8224, 12320)
    *(float4*)&smem[WG_OFF + 4 * t] = *(const float4*)&Wg[4 * t];

    float acc[8][8];
    #pragma unroll
    for (int i = 0; i < 8; ++i)
        #pragma unroll
        for (int j = 0; j < 8; ++j) acc[i][j] = 0.f;

    float4 wpr, xr;
    auto ISSUE = [&](int k0) {
        wpr = *(const float4*)&Wp[(size_t)wrow * D + k0 + wcol];
        if (t < 256) xr = *(const float4*)&x[(size_t)(tok0 + wrow) * D + k0 + wcol];
    };
    ISSUE(0);

    const float* wbase = &smem[WP_OFF + (hb * 128 + tx) * LDK + ku * 4];
    const float* xbase = &smem[X_OFF + tb * 128 + ku * 4];

    for (int c = 0; c < NCH; ++c) {
        __syncthreads();                     // prior chunk's reads done
        *(float4*)&smem[WP_OFF + wrow * LDK + wcol] = wpr;
        if (t < 256) *(float4*)&smem[X_OFF + wrow * 16 + wcol] = xr;
        __syncthreads();
        if (c + 1 < NCH) ISSUE((c + 1) * BK);   // prefetch under compute

        float4 xa[8];
        #pragma unroll
        for (int i = 0; i < 8; ++i)
            xa[i] = *(const float4*)&xbase[i * 16];   // broadcast reads
        #pragma unroll
        for (int j = 0; j < 8; ++j) {
            const float4 wvv = *(const float4*)&wbase[j * 16 * LDK];  // 64-distinct b128
            #pragma unroll
            for (int i = 0; i < 8; ++i) {
                acc[i][j] = fmaf(xa[i].x, wvv.x, acc[i][j]);
                acc[i][j] = fmaf(xa[i].y, wvv.y, acc[i][j]);
                acc[i][j] = fmaf(xa[i].z, wvv.z, acc[i][j]);
                acc[i][j] = fmaf(xa[i].w, wvv.w, acc[i][j]);
            }
        }
    }

    // ---- k-window reduction: in-wave butterflies over lane bits 4,5 ----
    #pragma unroll
    for (int i = 0; i < 8; ++i)
        #pragma unroll
        for (int j = 0; j < 8; ++j) {
            acc[i][j] += __shfl_xor(acc[i][j], 16);
            acc[i][j] += __shfl_xor(acc[i][j], 32);
        }

    __syncthreads();                          // staging region now dead

    const float temp = fabsf(temp_g[0]) + 1e-6f;
    float lnw[16], lnb[16];
    if (t < 512) {
        #pragma unroll
        for (int j = 0; j < 16; ++j) {
            lnw[j] = lnw_g[(t & 15) + 16 * j];
            lnb[j] = lnb_g[(t & 15) + 16 * j];
        }
    }
    float mylb = 0.f, myz = 0.f;

    // ---------- two post passes over 32-token halves ----------
    #pragma unroll
    for (int pass = 0; pass < 2; ++pass) {
        // dump this half's proj into SB [32][257]
        if (ku == 0 && (tb >> 2) == pass) {
            const int rb = (tb & 3) * 8;
            #pragma unroll
            for (int i = 0; i < 8; ++i)
                #pragma unroll
                for (int j = 0; j < 8; ++j)
                    smem[SB_OFF + (rb + i) * SB_LDW + hb * 128 + tx + 16 * j] = acc[i][j];
        }
        if (pass == 0) {
            if (t < 16)  smem[LB_OFF + t] = 0.f;
            if (t == 16) smem[Z_OFF] = 0.f;
        }
        __syncthreads();

        if (t < 512) {
            const int ptx  = t & 15;
            const int tokl = t >> 4;                  // 0..31
            const int tok  = tok0 + pass * 32 + tokl;

            float pr[16];
            #pragma unroll
            for (int j = 0; j < 16; ++j)
                pr[j] = smem[SB_OFF + tokl * SB_LDW + ptx + 16 * j];

            // mean / variance over H (16-lane butterfly)
            float s = 0.f;
            #pragma unroll
            for (int j = 0; j < 16; ++j) s += pr[j];
            s += __shfl_xor(s, 1); s += __shfl_xor(s, 2);
            s += __shfl_xor(s, 4); s += __shfl_xor(s, 8);
            const float mu = s * (1.f / 256.f);
            float v = 0.f;
            #pragma unroll
            for (int j = 0; j < 16; ++j) { const float d = pr[j] - mu; v = fmaf(d, d, v); }
            v += __shfl_xor(v, 1); v += __shfl_xor(v, 2);
            v += __shfl_xor(v, 4); v += __shfl_xor(v, 8);
            const float rstd = 1.0f / sqrtf(v * (1.f / 256.f) + 1e-5f);

            float n[16];
            #pragma unroll
            for (int j = 0; j < 16; ++j)
                n[j] = fmaf((pr[j] - mu) * rstd, lnw[j], lnb[j]);

            float p[16];
            #pragma unroll
            for (int e = 0; e < 16; ++e) p[e] = 0.f;
            #pragma unroll
            for (int j = 0; j < 16; ++j) {
                const float nv = n[j];
                const int  h   = ptx + 16 * j;
                #pragma unroll
                for (int e = 0; e < 16; ++e)
                    p[e] = fmaf(nv, smem[WG_OFF + e * H + h], p[e]);
            }
            #pragma unroll
            for (int m = 1; m < 16; m <<= 1)
                #pragma unroll
                for (int e = 0; e < 16; ++e) p[e] += __shfl_xor(p[e], m);
            #pragma unroll
            for (int e = 0; e < 16; ++e) p[e] = p[e] / temp;

            if (ptx == 0) {
                #pragma unroll
                for (int e = 0; e < 16; ++e) myz = fmaf(p[e], p[e], myz);
            }

            // softmax (stable)
            float mx = p[0];
            #pragma unroll
            for (int e = 1; e < 16; ++e) mx = fmaxf(mx, p[e]);
            float w[16]; float sw = 0.f;
            #pragma unroll
            for (int e = 0; e < 16; ++e) { w[e] = expf(p[e] - mx); sw += w[e]; }
            #pragma unroll
            for (int e = 0; e < 16; ++e) w[e] = w[e] / sw;
            mylb += w[ptx];

            // top-2 (ties -> lower index)
            float w1 = -1.f; int i1 = 0; float w2 = -1.f; int i2 = 0;
            #pragma unroll
            for (int e = 0; e < 16; ++e) {
                const float we = w[e];
                if (we > w1)      { w2 = w1; i2 = i1; w1 = we; i1 = e; }
                else if (we > w2) { w2 = we; i2 = e; }
            }
            const float rs = 1.f / (w1 + w2 + 1e-6f);
            out_rw  [(size_t)tok * E + ptx] = w[ptx];
            out_disp[(size_t)tok * E + ptx] = (ptx == i1) ? w1 * rs : (ptx == i2 ? w2 * rs : 0.f);
        }
        __syncthreads();
    }

    // ---- loss partials: reduce 4 tokens/wave in-register, then LDS atomics ----
    if (t < 512) {
        mylb += __shfl_xor(mylb, 16); mylb += __shfl_xor(mylb, 32);
        myz  += __shfl_xor(myz, 16);  myz  += __shfl_xor(myz, 32);
        if ((t & 63) < 16) atomicAdd(&smem[LB_OFF + (t & 15)], mylb);
        if ((t & 63) == 0) atomicAdd(&smem[Z_OFF], myz);
    }
    __syncthreads();
    if (t < 16)  ws_part[blockIdx.x * WS_STRIDE + t]  = smem[LB_OFF + t];
    if (t == 16) ws_part[blockIdx.x * WS_STRIDE + 16] = smem[Z_OFF];
}

__global__ void router_final(const float* __restrict__ ws_part,
                             float* __restrict__ out_loss, int nblocks, int T)
{
    const int l = threadIdx.x;   // 64 threads
    float lb[16]; float z = 0.f;
    #pragma unroll
    for (int e = 0; e < 16; ++e) lb[e] = 0.f;
    for (int b = l; b < nblocks; b += 64) {
        #pragma unroll
        for (int e = 0; e < 16; ++e) lb[e] += ws_part[b * WS_STRIDE + e];
        z += ws_part[b * WS_STRIDE + 16];
    }
    #pragma unroll
    for (int m = 1; m < 64; m <<= 1) {
        #pragma unroll
        for (int e = 0; e < 16; ++e) lb[e] += __shfl_xor(lb[e], m);
        z += __shfl_xor(z, m);
    }
    if (l == 0) {
        const float zloss = z / (float)(T * 16);
        const float ideal = 1.f / 16.f;
        float lbl = 0.f;
        #pragma unroll
        for (int e = 0; e < 16; ++e) {
            const float a = lb[e] / (float)T;
            lbl += ideal * (logf(ideal) - logf(a));
        }
        lbl *= (1.f / 16.f);
        out_loss[0] = 0.005f * zloss + 0.005f * lbl;
    }
}

extern "C" void kernel_launch(void* const* d_in, const int* in_sizes, int n_in,
                              void* d_out, int out_size, void* d_ws, size_t ws_size,
                              hipStream_t stream)
{
    const float* x    = (const float*)d_in[0];
    const float* Wp   = (const float*)d_in[1];
    const float* Wg   = (const float*)d_in[2];
    const float* lnw  = (const float*)d_in[3];
    const float* lnb  = (const float*)d_in[4];
    const float* temp = (const float*)d_in[5];
    const int T = in_sizes[0] / D;           // 16384
    float* out      = (float*)d_out;
    float* out_rw   = out;
    float* out_disp = out + (size_t)T * E;
    float* out_loss = out + (size_t)2 * T * E;
    float* ws_part  = (float*)d_ws;
    const int nblocks = T / TMB;             // 256

    hipLaunchKernelGGL(router_main, dim3(nblocks), dim3(THREADS), 0, stream,
                       x, Wp, Wg, lnw, lnb, temp, out_rw, out_disp, ws_part);
    hipLaunchKernelGGL(router_final, dim3(1), dim3(64), 0, stream,
                       ws_part, out_loss, nblocks, T);
}